// Round 11
// baseline (2252.079 us; speedup 1.0000x reference)
//
#include <hip/hip_runtime.h>
#include <hip/hip_bf16.h>

// HMM forward on MI355X — r8 algorithm (K=128 MX-fp8 MFMA, register-resident A,
// G-dot current-S normalization, exact telescope) with TWO CHAINS PER WORKGROUP:
// one barrier serves both chains' steps; chain-1 MFMA/LDS overlaps chain-0 tail.
// Per chain per step: acc = A v (16 MFMA/wave, 8 chains x depth 2);
// gv = G[x_t]·v (G = E^T A bf16, per-wave redundant dot, overlaps MFMA);
// w = E ⊙ acc; v' = w/gv (fp8, u=256 stable); L += log gv.
// Final step: exact reduction; out = L + log(Σw) − Tb·ln256.

typedef unsigned long long u64;
typedef unsigned int u32;
typedef unsigned short u16;
using f32x4 = __attribute__((ext_vector_type(4))) float;
using i32x8 = __attribute__((ext_vector_type(8))) int;

#define N_ST 512
#define VOCAB 10000
#define BATCH 64
#define T_MAX 1024

// ---------------- workspace layout (bytes) ----------------
#define WS_EB       0          // E bf16: 10000*512*2 = 10,240,000
#define WS_GB       10240000   // G bf16: 10,240,000
#define WS_A8       20480000   // 128 frags * 2048 B = 262,144
#define WS_ROWLSE   20742144   // 512 f32
#define WS_COLLSE   20744192   // 512 f32
#define WS_PINORM   20746240   // 512 f32

// ---- bf16 helpers ----
static __device__ __forceinline__ float bf16f(u16 h) {
    return __uint_as_float((u32)h << 16);
}
static __device__ __forceinline__ u16 bf16enc(float f) {
    u32 u = __float_as_uint(f);
    return (u16)((u + 0x7fffu + ((u >> 16) & 1u)) >> 16);
}

// ---- positive OCP e4m3fn decode ----
static __device__ __forceinline__ float dec8(u32 b) {
    float nrm = __uint_as_float((b << 20) + 0x3C000000u);
    float dnm = (float)b * 0x1p-9f;
    return b >= 8u ? nrm : dnm;
}

// ---- software e4m3fn encoder (fallback only) ----
static __device__ __forceinline__ u32 enc_e4m3(float f) {
    if (!(f > 0.f)) return 0u;
    unsigned u = __float_as_uint(f);
    int e = (int)((u >> 23) & 0xff) - 127;
    unsigned m = u & 0x7fffffu;
    if (e > 8 || (e == 8 && m >= 0x700000u)) return 0x7eu;
    if (e >= -6) {
        unsigned mant = m >> 20;
        unsigned rest = m & 0xfffffu;
        if (rest > 0x80000u || (rest == 0x80000u && (mant & 1u))) mant++;
        unsigned r = ((unsigned)(e + 7) << 3) + mant;
        return r > 0x7eu ? 0x7eu : r;
    }
    if (e < -10) return 0u;
    unsigned full = 0x800000u | m;
    int shift = 23 - (e + 9);
    unsigned r = full >> shift;
    unsigned rem = full & ((1u << shift) - 1u);
    unsigned half = 1u << (shift - 1);
    if (rem > half || (rem == half && (r & 1u))) r++;
    return r;
}

template <bool HI>
static __device__ __forceinline__ u32 cvtpk2(float a, float b, u32 old) {
#if __has_builtin(__builtin_amdgcn_cvt_pk_fp8_f32)
    return (u32)__builtin_amdgcn_cvt_pk_fp8_f32(a, b, (int)old, HI);
#else
    unsigned v = enc_e4m3(a) | (enc_e4m3(b) << 8);
    return HI ? ((old & 0x0000ffffu) | (v << 16)) : ((old & 0xffff0000u) | v);
#endif
}

// ---- rowLSE[n] = logsumexp_m emit[n, m] ----
__global__ __launch_bounds__(256) void k_row_lse(const float* __restrict__ emit,
                                                 float* __restrict__ rowLSE) {
    const int n = blockIdx.x;
    const float* row = emit + (size_t)n * VOCAB;
    __shared__ float redm[4], reds[4];
    const int tid = threadIdx.x, lane = tid & 63, wid = tid >> 6;

    float m = -INFINITY;
    for (int i = tid; i < VOCAB; i += 256) m = fmaxf(m, row[i]);
    #pragma unroll
    for (int o = 32; o; o >>= 1) m = fmaxf(m, __shfl_down(m, o));
    if (lane == 0) redm[wid] = m;
    __syncthreads();
    if (tid == 0) redm[0] = fmaxf(fmaxf(redm[0], redm[1]), fmaxf(redm[2], redm[3]));
    __syncthreads();
    m = redm[0];

    float s = 0.f;
    for (int i = tid; i < VOCAB; i += 256) s += __expf(row[i] - m);
    #pragma unroll
    for (int o = 32; o; o >>= 1) s += __shfl_down(s, o);
    if (lane == 0) reds[wid] = s;
    __syncthreads();
    if (tid == 0) rowLSE[n] = m + __logf(reds[0] + reds[1] + reds[2] + reds[3]);
}

// ---- Eb[m*512+n] = bf16( exp(emit[n,m] - rowLSE[n]) ) ----
__global__ __launch_bounds__(256) void k_expEmitT(const float* __restrict__ emit,
                                                  const float* __restrict__ rowLSE,
                                                  u16* __restrict__ Eb) {
    const size_t gid = (size_t)blockIdx.x * 256 + threadIdx.x;
    const int m = (int)(gid >> 9);
    const int n = (int)(gid & 511);
    Eb[gid] = bf16enc(__expf(emit[(size_t)n * VOCAB + m] - rowLSE[n]));
}

// ---- colLSE[k] = logsumexp_j trans[j, k] ----
__global__ __launch_bounds__(256) void k_col_lse(const float* __restrict__ trans,
                                                 float* __restrict__ colLSE) {
    const int k = blockIdx.x;
    const int tid = threadIdx.x, lane = tid & 63, wid = tid >> 6;
    __shared__ float redm[4], reds[4];

    float a = trans[(size_t)tid * N_ST + k];
    float b = trans[(size_t)(tid + 256) * N_ST + k];
    float m = fmaxf(a, b);
    #pragma unroll
    for (int o = 32; o; o >>= 1) m = fmaxf(m, __shfl_down(m, o));
    if (lane == 0) redm[wid] = m;
    __syncthreads();
    if (tid == 0) redm[0] = fmaxf(fmaxf(redm[0], redm[1]), fmaxf(redm[2], redm[3]));
    __syncthreads();
    m = redm[0];

    float s = __expf(a - m) + __expf(b - m);
    #pragma unroll
    for (int o = 32; o; o >>= 1) s += __shfl_down(s, o);
    if (lane == 0) reds[wid] = s;
    __syncthreads();
    if (tid == 0) colLSE[k] = m + __logf(reds[0] + reds[1] + reds[2] + reds[3]);
}

// ---- pack A (column-softmax of trans, x256) into fp8 K=128 MFMA A-fragments ----
__global__ __launch_bounds__(64) void k_packA_fp8(const float* __restrict__ trans,
                                                  const float* __restrict__ colLSE,
                                                  u32* __restrict__ A8) {
    const int f = blockIdx.x;        // 0..127
    const int l = threadIdx.x;       // 0..63
    const int w = f >> 4, ks = (f >> 2) & 3, jt = f & 3;
    const int j = w * 64 + jt * 16 + (l & 15);
    const int k0 = ks * 128 + (l >> 4) * 32;
    u32 dw[8];
    #pragma unroll
    for (int d = 0; d < 8; ++d) {
        float a0 = 256.0f * __expf(trans[(size_t)j * N_ST + k0 + 4 * d + 0] - colLSE[k0 + 4 * d + 0]);
        float a1 = 256.0f * __expf(trans[(size_t)j * N_ST + k0 + 4 * d + 1] - colLSE[k0 + 4 * d + 1]);
        float a2 = 256.0f * __expf(trans[(size_t)j * N_ST + k0 + 4 * d + 2] - colLSE[k0 + 4 * d + 2]);
        float a3 = 256.0f * __expf(trans[(size_t)j * N_ST + k0 + 4 * d + 3] - colLSE[k0 + 4 * d + 3]);
        u32 pk = cvtpk2<false>(a0, a1, 0u);
        dw[d] = cvtpk2<true>(a2, a3, pk);
    }
    u32* dst = A8 + (size_t)f * 512 + l * 8;
    *(uint4*)dst       = make_uint4(dw[0], dw[1], dw[2], dw[3]);
    *(uint4*)(dst + 4) = make_uint4(dw[4], dw[5], dw[6], dw[7]);
}

// ---- pinorm[j] = softmax(priors)[j] ----
__global__ __launch_bounds__(512) void k_pinorm(const float* __restrict__ priors,
                                                float* __restrict__ pinorm) {
    const int j = threadIdx.x, lane = j & 63, wid = j >> 6;
    __shared__ float redm[8], reds[8];
    float v = priors[j];

    float m = v;
    #pragma unroll
    for (int o = 32; o; o >>= 1) m = fmaxf(m, __shfl_down(m, o));
    if (lane == 0) redm[wid] = m;
    __syncthreads();
    if (j == 0) {
        float r = redm[0];
        for (int i = 1; i < 8; ++i) r = fmaxf(r, redm[i]);
        redm[0] = r;
    }
    __syncthreads();
    m = redm[0];

    float s = __expf(v - m);
    #pragma unroll
    for (int o = 32; o; o >>= 1) s += __shfl_down(s, o);
    if (lane == 0) reds[wid] = s;
    __syncthreads();
    if (j == 0) {
        float r = 0.f;
        for (int i = 0; i < 8; ++i) r += reds[i];
        reds[0] = r;
    }
    __syncthreads();
    pinorm[j] = __expf(v - m) / reds[0];
}

// ---- G[m][k] = sum_j E[m][j] * A[j][k] (true A) ----
__global__ __launch_bounds__(256) void k_G(const u16* __restrict__ Eb,
                                           const float* __restrict__ trans,
                                           const float* __restrict__ colLSE,
                                           u16* __restrict__ Gb) {
    __shared__ float Es[16][512];
    const int m0 = blockIdx.x * 16;
    const int tid = threadIdx.x;
    for (int idx = tid; idx < 16 * 512; idx += 256)
        Es[idx >> 9][idx & 511] = bf16f(Eb[(size_t)(m0 + (idx >> 9)) * 512 + (idx & 511)]);
    __syncthreads();

    const int k0 = tid, k1 = tid + 256;
    const float c0 = colLSE[k0], c1 = colLSE[k1];
    float acc0[16], acc1[16];
    #pragma unroll
    for (int mi = 0; mi < 16; ++mi) { acc0[mi] = 0.f; acc1[mi] = 0.f; }

    for (int j = 0; j < 512; ++j) {
        float a0 = __expf(trans[(size_t)j * N_ST + k0] - c0);
        float a1 = __expf(trans[(size_t)j * N_ST + k1] - c1);
        #pragma unroll
        for (int mi = 0; mi < 16; ++mi) {
            float e = Es[mi][j];
            acc0[mi] = fmaf(e, a0, acc0[mi]);
            acc1[mi] = fmaf(e, a1, acc1[mi]);
        }
    }
    #pragma unroll
    for (int mi = 0; mi < 16; ++mi) {
        Gb[(size_t)(m0 + mi) * N_ST + k0] = bf16enc(acc0[mi]);
        Gb[(size_t)(m0 + mi) * N_ST + k1] = bf16enc(acc1[mi]);
    }
}

#define UNIT_SCALES 0x7f7f7f7f   // 4x e8m0 "1.0"
#define LN256 5.545177444479562f

// raw workgroup barrier: drain LDS only (vmem prefetch stays in flight)
#define WG_BARRIER()                                        \
  {                                                         \
    asm volatile("s_waitcnt lgkmcnt(0)" ::: "memory");      \
    __builtin_amdgcn_s_barrier();                           \
    asm volatile("" ::: "memory");                          \
  }

// pre-barrier work for one chain (identical math to the passing r8 kernel)
#define CHAIN_PRE(SUF, EU, GU, EP, GP)                                          \
  if (t <= Tf##SUF) {                                                           \
    const int xpre = xnext##SUF;                                                \
    GP = *(const uint4*)((const char*)Gb + ((size_t)xpre << 10) + (l << 4));    \
    _Pragma("unroll")                                                           \
    for (int jt = 0; jt < 4; ++jt)                                              \
      EP[jt] = *(const u64*)(Eb + (size_t)xpre * N_ST + wbase + jt * 16 + rbase); \
    xnext##SUF = xb##SUF[(t + 2 <= Tf##SUF) ? (t + 2) : Tf##SUF];               \
    const u64 vown = vq##SUF[p][l];                                             \
    const u32* vbase = (const u32*)&vq##SUF[p][0];                              \
    i32x8 bq[4];                                                                \
    _Pragma("unroll")                                                           \
    for (int ks = 0; ks < 4; ++ks) {                                            \
      const uint4 b0 = *(const uint4*)(vbase + ks * 32 + grp * 8);              \
      const uint4 b1 = *(const uint4*)(vbase + ks * 32 + grp * 8 + 4);          \
      bq[ks] = i32x8{(int)b0.x, (int)b0.y, (int)b0.z, (int)b0.w,                \
                     (int)b1.x, (int)b1.y, (int)b1.z, (int)b1.w};               \
    }                                                                           \
    f32x4 aA0={0,0,0,0}, aA1={0,0,0,0}, aA2={0,0,0,0}, aA3={0,0,0,0};           \
    f32x4 aB0={0,0,0,0}, aB1={0,0,0,0}, aB2={0,0,0,0}, aB3={0,0,0,0};           \
    _Pragma("unroll")                                                           \
    for (int kk = 0; kk < 2; ++kk) {                                            \
      const int ksA = kk * 2, ksB = kk * 2 + 1;                                 \
      aA0 = __builtin_amdgcn_mfma_scale_f32_16x16x128_f8f6f4(                   \
                af[ksA * 4 + 0], bq[ksA], aA0, 0, 0, 0, UNIT_SCALES, 0, UNIT_SCALES); \
      aB0 = __builtin_amdgcn_mfma_scale_f32_16x16x128_f8f6f4(                   \
                af[ksB * 4 + 0], bq[ksB], aB0, 0, 0, 0, UNIT_SCALES, 0, UNIT_SCALES); \
      aA1 = __builtin_amdgcn_mfma_scale_f32_16x16x128_f8f6f4(                   \
                af[ksA * 4 + 1], bq[ksA], aA1, 0, 0, 0, UNIT_SCALES, 0, UNIT_SCALES); \
      aB1 = __builtin_amdgcn_mfma_scale_f32_16x16x128_f8f6f4(                   \
                af[ksB * 4 + 1], bq[ksB], aB1, 0, 0, 0, UNIT_SCALES, 0, UNIT_SCALES); \
      aA2 = __builtin_amdgcn_mfma_scale_f32_16x16x128_f8f6f4(                   \
                af[ksA * 4 + 2], bq[ksA], aA2, 0, 0, 0, UNIT_SCALES, 0, UNIT_SCALES); \
      aB2 = __builtin_amdgcn_mfma_scale_f32_16x16x128_f8f6f4(                   \
                af[ksB * 4 + 2], bq[ksB], aB2, 0, 0, 0, UNIT_SCALES, 0, UNIT_SCALES); \
      aA3 = __builtin_amdgcn_mfma_scale_f32_16x16x128_f8f6f4(                   \
                af[ksA * 4 + 3], bq[ksA], aA3, 0, 0, 0, UNIT_SCALES, 0, UNIT_SCALES); \
      aB3 = __builtin_amdgcn_mfma_scale_f32_16x16x128_f8f6f4(                   \
                af[ksB * 4 + 3], bq[ksB], aB3, 0, 0, 0, UNIT_SCALES, 0, UNIT_SCALES); \
    }                                                                           \
    float gv = 0.f;                                                             \
    {                                                                           \
      const u32 gw[4] = {GU.x, GU.y, GU.z, GU.w};                               \
      _Pragma("unroll")                                                         \
      for (int i = 0; i < 4; ++i) {                                             \
        float g0 = bf16f((u16)(gw[i] & 0xffffu));                               \
        float g1 = bf16f((u16)(gw[i] >> 16));                                   \
        float v0 = dec8((u32)(vown >> (16 * i)) & 0xffu);                       \
        float v1 = dec8((u32)(vown >> (16 * i + 8)) & 0xffu);                   \
        gv = fmaf(g0, v0, gv);                                                  \
        gv = fmaf(g1, v1, gv);                                                  \
      }                                                                         \
      _Pragma("unroll")                                                         \
      for (int o = 1; o <= 32; o <<= 1) gv += __shfl_xor(gv, o);                \
    }                                                                           \
    float wv2[16];                                                              \
    _Pragma("unroll")                                                           \
    for (int r = 0; r < 4; ++r) {                                               \
      wv2[0 + r]  = bf16f((u16)(EU[0] >> (16 * r))) * (aA0[r] + aB0[r]);        \
      wv2[4 + r]  = bf16f((u16)(EU[1] >> (16 * r))) * (aA1[r] + aB1[r]);        \
      wv2[8 + r]  = bf16f((u16)(EU[2] >> (16 * r))) * (aA2[r] + aB2[r]);        \
      wv2[12 + r] = bf16f((u16)(EU[3] >> (16 * r))) * (aA3[r] + aB3[r]);        \
    }                                                                           \
    if (t == Tf##SUF) {                                                         \
      float s2 = 0.f;                                                           \
      _Pragma("unroll")                                                         \
      for (int i = 0; i < 16; ++i) s2 += wv2[i];                                \
      s2 += __shfl_xor(s2, 16);                                                 \
      s2 += __shfl_xor(s2, 32);                                                 \
      if (l == 0) redF##SUF[wid] = s2;                                          \
    } else {                                                                    \
      L##SUF += __logf(gv);                                                     \
      const float sc = 1.0f / gv;                                               \
      if ((l & 15) == 0) {                                                      \
        u32* vw = (u32*)&vq##SUF[p ^ 1][0];                                     \
        _Pragma("unroll")                                                       \
        for (int jt = 0; jt < 4; ++jt) {                                        \
          u32 pk = cvtpk2<false>(wv2[jt * 4 + 0] * sc, wv2[jt * 4 + 1] * sc, 0u); \
          pk = cvtpk2<true>(wv2[jt * 4 + 2] * sc, wv2[jt * 4 + 3] * sc, pk);    \
          vw[(wbase >> 2) + jt * 4 + grp] = pk;                                 \
        }                                                                       \
      }                                                                         \
    }                                                                           \
  }

// post-barrier final output for one chain
#define CHAIN_POST(SUF, CIDX)                                                   \
  if (t == Tf##SUF && Tb##SUF > 1) {                                            \
    const float Se = redF##SUF[0] + redF##SUF[1] + redF##SUF[2] + redF##SUF[3] +\
                     redF##SUF[4] + redF##SUF[5] + redF##SUF[6] + redF##SUF[7]; \
    if (tid == 0) out[CIDX] = L##SUF + __logf(Se) - (float)Tb##SUF * LN256;     \
  }

#define ITER(EU0, GU0, EP0, GP0, EU1, GU1, EP1, GP1)                            \
  {                                                                             \
    CHAIN_PRE(0, EU0, GU0, EP0, GP0)                                            \
    CHAIN_PRE(1, EU1, GU1, EP1, GP1)                                            \
    WG_BARRIER();                                                               \
    CHAIN_POST(0, c0)                                                           \
    CHAIN_POST(1, c1)                                                           \
  }

// ---- main: one WG per TWO chains; 8 waves x 64 states; shared A frags ----
__global__ __launch_bounds__(512, 2) void hmm_main(const int* __restrict__ x,
                                                   const int* __restrict__ T,
                                                   const u16* __restrict__ Eb,
                                                   const u32* __restrict__ A8,
                                                   const u16* __restrict__ Gb,
                                                   const float* __restrict__ pinorm,
                                                   float* __restrict__ out) {
    __shared__ __align__(16) u64 vq0[2][64];
    __shared__ __align__(16) u64 vq1[2][64];
    __shared__ __align__(16) float redF0[8];
    __shared__ __align__(16) float redF1[8];
    const int c0 = 2 * blockIdx.x;
    const int c1 = 2 * blockIdx.x + 1;
    const int tid = threadIdx.x;
    const int l = tid & 63;
    const int wid = tid >> 6;
    const int grp = l >> 4;
    const int wbase = wid * 64;
    const int rbase = grp * 4;

    int Tb0 = T[c0]; Tb0 = Tb0 < 1 ? 1 : (Tb0 > T_MAX ? T_MAX : Tb0);
    int Tb1 = T[c1]; Tb1 = Tb1 < 1 ? 1 : (Tb1 > T_MAX ? T_MAX : Tb1);
    const int* xb0 = x + (size_t)c0 * T_MAX;
    const int* xb1 = x + (size_t)c1 * T_MAX;
    const int Tf0 = Tb0 - 1;
    const int Tf1 = Tb1 - 1;
    const int Tmax = Tf0 > Tf1 ? Tf0 : Tf1;

    // resident A fragments: shared by both chains (same matrix), 128 regs
    i32x8 af[16];
    {
        const u32* ap = A8 + (size_t)wid * 16 * 512 + l * 8;
        #pragma unroll
        for (int i = 0; i < 16; ++i) {
            uint4 lo = *(const uint4*)(ap + (size_t)i * 512);
            uint4 hi = *(const uint4*)(ap + (size_t)i * 512 + 4);
            af[i] = i32x8{(int)lo.x, (int)lo.y, (int)lo.z, (int)lo.w,
                          (int)hi.x, (int)hi.y, (int)hi.z, (int)hi.w};
        }
    }

    // prefetch E/G for t=1, both chains (x valid up to T_MAX)
    u64 eA0[4], eB0[4], eA1[4], eB1[4];
    uint4 gA0, gB0, gA1, gB1;
    {
        const int x10 = xb0[1];
        const int x11 = xb1[1];
        gA0 = *(const uint4*)((const char*)Gb + ((size_t)x10 << 10) + (l << 4));
        gA1 = *(const uint4*)((const char*)Gb + ((size_t)x11 << 10) + (l << 4));
        #pragma unroll
        for (int jt = 0; jt < 4; ++jt) {
            eA0[jt] = *(const u64*)(Eb + (size_t)x10 * N_ST + wbase + jt * 16 + rbase);
            eA1[jt] = *(const u64*)(Eb + (size_t)x11 * N_ST + wbase + jt * 16 + rbase);
        }
    }

    // ---- t = 0, both chains ----
    float wv_0[16], wv_1[16];
    {
        const int x00 = xb0[0];
        const int x01 = xb1[0];
        float s0 = 0.f, s1 = 0.f;
        #pragma unroll
        for (int jt = 0; jt < 4; ++jt) {
            u64 er0 = *(const u64*)(Eb + (size_t)x00 * N_ST + wbase + jt * 16 + rbase);
            u64 er1 = *(const u64*)(Eb + (size_t)x01 * N_ST + wbase + jt * 16 + rbase);
            #pragma unroll
            for (int r = 0; r < 4; ++r) {
                const int j = wbase + jt * 16 + rbase + r;
                const float pj = pinorm[j];
                float t0 = bf16f((u16)(er0 >> (16 * r))) * pj;
                float t1 = bf16f((u16)(er1 >> (16 * r))) * pj;
                wv_0[jt * 4 + r] = t0;  s0 += t0;
                wv_1[jt * 4 + r] = t1;  s1 += t1;
            }
        }
        s0 += __shfl_xor(s0, 16);  s0 += __shfl_xor(s0, 32);
        s1 += __shfl_xor(s1, 16);  s1 += __shfl_xor(s1, 32);
        if (l == 0) { redF0[wid] = s0; redF1[wid] = s1; }
    }
    __syncthreads();
    const float S00 = redF0[0] + redF0[1] + redF0[2] + redF0[3] +
                      redF0[4] + redF0[5] + redF0[6] + redF0[7];
    const float S01 = redF1[0] + redF1[1] + redF1[2] + redF1[3] +
                      redF1[4] + redF1[5] + redF1[6] + redF1[7];
    float L0 = __logf(S00);
    float L1 = __logf(S01);
    if (Tb0 == 1 && tid == 0) out[c0] = L0;
    if (Tb1 == 1 && tid == 0) out[c1] = L1;
    if (Tmax == 0) return;
    __syncthreads();
    {
        const float sc0 = 256.0f / S00;
        const float sc1 = 256.0f / S01;
        if ((l & 15) == 0) {
            u32* vw0 = (u32*)&vq0[0][0];
            u32* vw1 = (u32*)&vq1[0][0];
            #pragma unroll
            for (int jt = 0; jt < 4; ++jt) {
                u32 pk0 = cvtpk2<false>(wv_0[jt * 4 + 0] * sc0, wv_0[jt * 4 + 1] * sc0, 0u);
                pk0 = cvtpk2<true>(wv_0[jt * 4 + 2] * sc0, wv_0[jt * 4 + 3] * sc0, pk0);
                vw0[(wbase >> 2) + jt * 4 + grp] = pk0;
                u32 pk1 = cvtpk2<false>(wv_1[jt * 4 + 0] * sc1, wv_1[jt * 4 + 1] * sc1, 0u);
                pk1 = cvtpk2<true>(wv_1[jt * 4 + 2] * sc1, wv_1[jt * 4 + 3] * sc1, pk1);
                vw1[(wbase >> 2) + jt * 4 + grp] = pk1;
            }
        }
    }
    __syncthreads();

    // ---- t = 1 .. Tmax (one barrier per iteration serves both chains) ----
    int p = 0;
    int xnext0 = xb0[(2 <= Tf0) ? 2 : Tf0];
    int xnext1 = xb1[(2 <= Tf1) ? 2 : Tf1];
    for (int t = 1;;) {
        ITER(eA0, gA0, eB0, gB0, eA1, gA1, eB1, gB1)
        p ^= 1;
        if (t == Tmax) break;
        ++t;
        ITER(eB0, gB0, eA0, gA0, eB1, gB1, eA1, gA1)
        p ^= 1;
        if (t == Tmax) break;
        ++t;
    }
}

extern "C" void kernel_launch(void* const* d_in, const int* in_sizes, int n_in,
                              void* d_out, int out_size, void* d_ws, size_t ws_size,
                              hipStream_t stream) {
    const int*   x      = (const int*)d_in[0];     // (64, 1024)
    const int*   T      = (const int*)d_in[1];     // (64,)
    const float* priors = (const float*)d_in[2];   // (512,)
    const float* trans  = (const float*)d_in[3];   // (512, 512)
    const float* emit   = (const float*)d_in[4];   // (512, 10000)
    float* out = (float*)d_out;                    // (64, 1)

    char* ws = (char*)d_ws;
    u16*   Eb     = (u16*)(ws + WS_EB);
    u16*   Gb     = (u16*)(ws + WS_GB);
    u32*   A8     = (u32*)(ws + WS_A8);
    float* rowLSE = (float*)(ws + WS_ROWLSE);
    float* colLSE = (float*)(ws + WS_COLLSE);
    float* pinorm = (float*)(ws + WS_PINORM);

    k_row_lse<<<N_ST, 256, 0, stream>>>(emit, rowLSE);
    k_expEmitT<<<(VOCAB * N_ST) / 256, 256, 0, stream>>>(emit, rowLSE, Eb);
    k_col_lse<<<N_ST, 256, 0, stream>>>(trans, colLSE);
    k_packA_fp8<<<128, 64, 0, stream>>>(trans, colLSE, A8);
    k_pinorm<<<1, 512, 0, stream>>>(priors, pinorm);
    k_G<<<VOCAB / 16, 256, 0, stream>>>(Eb, trans, colLSE, Gb);

    hmm_main<<<BATCH / 2, 512, 0, stream>>>(x, T, Eb, A8, Gb, pinorm, out);
}